// Round 2
// baseline (12720.163 us; speedup 1.0000x reference)
//
#include <hip/hip_runtime.h>
#include <hip/hip_bf16.h>

#define BB 8
#define NN 1024
#define DD 128
#define HH 4
#define LL 4

__device__ __forceinline__ unsigned short f2bf(float f) {
  union { float f; unsigned int u; } v; v.f = f;
  unsigned int u = v.u;
  unsigned int r = (u + 0x7FFFu + ((u >> 16) & 1u)) >> 16;
  return (unsigned short)r;
}
__device__ __forceinline__ float bf2f(unsigned short s) {
  union { unsigned int u; float f; } v; v.u = ((unsigned int)s) << 16;
  return v.f;
}

// ---------------- adj transpose to bf16: out[b][r][p] = bf16(in[b][p][r]) -----
__global__ __launch_bounds__(256) void k_transpose_bf16(const float* __restrict__ in,
                                                        unsigned short* __restrict__ out) {
  __shared__ float t[32][33];
  int b = blockIdx.z;
  int x0 = blockIdx.x * 32, y0 = blockIdx.y * 32;
  int tx = threadIdx.x & 31, ty = threadIdx.x >> 5; // 32 x 8
  const float* ib = in + (size_t)b * NN * NN;
  unsigned short* ob = out + (size_t)b * NN * NN;
#pragma unroll
  for (int j = 0; j < 32; j += 8)
    t[ty + j][tx] = ib[(size_t)(y0 + ty + j) * NN + x0 + tx];
  __syncthreads();
#pragma unroll
  for (int j = 0; j < 32; j += 8)
    ob[(size_t)(x0 + ty + j) * NN + y0 + tx] = f2bf(t[tx][ty + j]);
}

// ---------------- generic K=128 GEMM: C[M,Nn] = A[M,128] @ Bw[128,Nn] (+bias) ----
__global__ __launch_bounds__(256) void k_gemm_k128(const float* __restrict__ A,
                                                   const float* __restrict__ Bw,
                                                   const float* __restrict__ bias,
                                                   float* __restrict__ C,
                                                   int M, int Nn) {
  __shared__ __align__(16) float As[32][68]; // [k][m]
  __shared__ __align__(16) float Bs[32][68]; // [k][n]
  const int tm = blockIdx.x * 64, tn = blockIdx.y * 64;
  const int tid = threadIdx.x;
  const int ty = tid >> 4, tx = tid & 15;
  float acc[4][4] = {};
  for (int kc = 0; kc < 128; kc += 32) {
#pragma unroll
    for (int e = 0; e < 8; ++e) {
      int fl = tid + e * 256;
      int r = fl >> 5, k = fl & 31;
      As[k][r] = A[(size_t)(tm + r) * 128 + kc + k];
    }
#pragma unroll
    for (int e = 0; e < 8; ++e) {
      int fl = tid + e * 256;
      int k = fl >> 6, n = fl & 63;
      Bs[k][n] = Bw[(size_t)(kc + k) * Nn + tn + n];
    }
    __syncthreads();
#pragma unroll
    for (int kk = 0; kk < 32; ++kk) {
      float a4[4], b4[4];
      *(float4*)a4 = *(const float4*)&As[kk][ty * 4];
      *(float4*)b4 = *(const float4*)&Bs[kk][tx * 4];
#pragma unroll
      for (int i = 0; i < 4; ++i)
#pragma unroll
        for (int j = 0; j < 4; ++j) acc[i][j] += a4[i] * b4[j];
    }
    __syncthreads();
  }
#pragma unroll
  for (int i = 0; i < 4; ++i) {
    float o4[4];
#pragma unroll
    for (int j = 0; j < 4; ++j) {
      float v = acc[i][j];
      if (bias) v += bias[tn + tx * 4 + j];
      o4[j] = v;
    }
    *(float4*)&C[(size_t)(tm + ty * 4 + i) * Nn + tn + tx * 4] = *(float4*)o4;
  }
}

// ------- E[gi,p,r] = dot(g[p],h[r]) + dot(g[r],h[p]) (symmetric), batch group ---
__global__ __launch_bounds__(256) void k_e(const float* __restrict__ g,
                                           const float* __restrict__ h,
                                           float* __restrict__ e, int b0) {
  const int tp = blockIdx.x, tr = blockIdx.y;
  if (tp > tr) return; // symmetric: upper-triangular tile pairs only
  const int gi = blockIdx.z;                 // local (bLocal*H + i)
  const int b = b0 + (gi >> 2), i = gi & 3;  // global batch
  const int p0 = tp * 64, r0 = tr * 64;
  __shared__ __align__(16) float Gp[32][68], Hp[32][68], Gr[32][68], Hr[32][68];
  const int tid = threadIdx.x;
  const int ty = tid >> 4, tx = tid & 15;
  float acc[4][4] = {};
  const float* gb = g + (size_t)b * NN * (HH * DD) + i * DD;
  const float* hb = h + (size_t)b * NN * (HH * DD) + i * DD;
  for (int kc = 0; kc < 128; kc += 32) {
#pragma unroll
    for (int e2 = 0; e2 < 8; ++e2) {
      int fl = tid + e2 * 256;
      int rr = fl >> 5, kk = fl & 31;
      Gp[kk][rr] = gb[(size_t)(p0 + rr) * 512 + kc + kk];
      Hp[kk][rr] = hb[(size_t)(p0 + rr) * 512 + kc + kk];
      Gr[kk][rr] = gb[(size_t)(r0 + rr) * 512 + kc + kk];
      Hr[kk][rr] = hb[(size_t)(r0 + rr) * 512 + kc + kk];
    }
    __syncthreads();
#pragma unroll
    for (int kk = 0; kk < 32; ++kk) {
      float gp[4], hp[4], gr[4], hr[4];
      *(float4*)gp = *(const float4*)&Gp[kk][ty * 4];
      *(float4*)hp = *(const float4*)&Hp[kk][ty * 4];
      *(float4*)gr = *(const float4*)&Gr[kk][tx * 4];
      *(float4*)hr = *(const float4*)&Hr[kk][tx * 4];
#pragma unroll
      for (int a = 0; a < 4; ++a)
#pragma unroll
        for (int c2 = 0; c2 < 4; ++c2)
          acc[a][c2] += gp[a] * hr[c2] + gr[c2] * hp[a];
    }
    __syncthreads();
  }
  float* eb = e + (size_t)gi * NN * NN;
#pragma unroll
  for (int a = 0; a < 4; ++a) {
    float v4[4];
#pragma unroll
    for (int c2 = 0; c2 < 4; ++c2) v4[c2] = acc[a][c2];
    *(float4*)&eb[(size_t)(p0 + ty * 4 + a) * NN + r0 + tx * 4] = *(float4*)v4;
  }
  if (tp != tr) { // transposed copy (skip on diagonal: already covered, avoids race)
#pragma unroll
    for (int c2 = 0; c2 < 4; ++c2) {
      float v4[4];
#pragma unroll
      for (int a = 0; a < 4; ++a) v4[a] = acc[a][c2];
      *(float4*)&eb[(size_t)(r0 + tx * 4 + c2) * NN + p0 + ty * 4] = *(float4*)v4;
    }
  }
}

// --------- softmax over p per column r, * adj; writes bf16 attT overlaid in e --
// E row (gi,r,:) == column r by symmetry. attT[gi,r,p] stored as ushort in the
// first 2048 bytes of the same e row (block-private; reads precede writes).
__global__ __launch_bounds__(256) void k_soft(float* __restrict__ e,
                                              const unsigned short* __restrict__ adjT,
                                              const float* __restrict__ adj, int b0) {
  const int col = blockIdx.x;            // local (gi)*N + r
  const int r = col & (NN - 1);
  const int gi = col >> 10;
  const int b = b0 + (gi >> 2);
  const float* erow = e + (size_t)col * NN;
  const unsigned short* atrow = adjT ? adjT + ((size_t)b * NN + r) * NN : nullptr;
  const float* acol = adj + (size_t)b * NN * NN + r; // adj[b][p][r], stride NN
  const int tid = threadIdx.x;
  float sv[4], av[4], ex[4];
  float mx = -1e30f;
#pragma unroll
  for (int j = 0; j < 4; ++j) {
    int p = tid + j * 256;
    float a = atrow ? bf2f(atrow[p]) : acol[(size_t)p * NN];
    av[j] = a;
    float ev = erow[p];
    float s = (a > 0.f) ? ev : 0.f;
    sv[j] = s;
    mx = fmaxf(mx, s);
  }
  __shared__ float sm[4], ssum[4];
  const int wid = tid >> 6, lane = tid & 63;
#pragma unroll
  for (int off = 32; off; off >>= 1) mx = fmaxf(mx, __shfl_xor(mx, off));
  if (lane == 0) sm[wid] = mx;
  __syncthreads();
  mx = fmaxf(fmaxf(sm[0], sm[1]), fmaxf(sm[2], sm[3]));
  float psum = 0.f;
#pragma unroll
  for (int j = 0; j < 4; ++j) {
    ex[j] = expf(sv[j] - mx); // masked: exp(0-mx) — counts in denominator
    psum += ex[j];
  }
#pragma unroll
  for (int off = 32; off; off >>= 1) psum += __shfl_xor(psum, off);
  if (lane == 0) ssum[wid] = psum;
  __syncthreads();
  float inv = 1.f / (ssum[0] + ssum[1] + ssum[2] + ssum[3]);
  unsigned short* attrow = (unsigned short*)erow; // overlay: first half of row
#pragma unroll
  for (int j = 0; j < 4; ++j) {
    int p = tid + j * 256;
    float att = (av[j] > 0.f) ? ex[j] * inv * av[j] : 0.f;
    attrow[p] = f2bf(att);
  }
}

// ---------------- az[p,q] = relu( sum_r attT[r,p] * z[r,q] ) per (group,head) --
__global__ __launch_bounds__(256) void k_az(const float* __restrict__ eAtt,
                                            const float* __restrict__ zin,
                                            float* __restrict__ azout, int b0) {
  const int p0 = blockIdx.x * 32;
  const int gi = blockIdx.y;                 // local (bLocal*H + i)
  const int b = b0 + (gi >> 2), i = gi & 3;
  __shared__ __align__(16) float At[32][36];   // [r][p]
  __shared__ __align__(16) float Zs[32][132];  // [r][q]
  const int tid = threadIdx.x;
  const int ty = tid >> 5, tx = tid & 31;
  float acc[4][4] = {};
  const unsigned short* ab = (const unsigned short*)eAtt;
  const float* zb = zin + (size_t)b * NN * 512 + i * DD;
  for (int rc = 0; rc < NN; rc += 32) {
#pragma unroll
    for (int j = 0; j < 4; ++j) {
      int fl = tid + j * 256;
      int rr = fl >> 5, pp = fl & 31;
      At[rr][pp] = bf2f(ab[((size_t)gi * NN + rc + rr) * (2 * NN) + p0 + pp]);
    }
#pragma unroll
    for (int j = 0; j < 16; ++j) {
      int fl = tid + j * 256;
      int rr = fl >> 7, qq = fl & 127;
      Zs[rr][qq] = zb[(size_t)(rc + rr) * 512 + qq];
    }
    __syncthreads();
#pragma unroll
    for (int rr = 0; rr < 32; ++rr) {
      float a4[4], z4[4];
      *(float4*)a4 = *(const float4*)&At[rr][ty * 4];
      *(float4*)z4 = *(const float4*)&Zs[rr][tx * 4];
#pragma unroll
      for (int a = 0; a < 4; ++a)
#pragma unroll
        for (int q = 0; q < 4; ++q) acc[a][q] += a4[a] * z4[q];
    }
    __syncthreads();
  }
  float* ob = azout + (size_t)b * NN * 512 + i * DD;
#pragma unroll
  for (int a = 0; a < 4; ++a) {
    float o4[4];
#pragma unroll
    for (int q = 0; q < 4; ++q) o4[q] = fmaxf(acc[a][q], 0.f);
    *(float4*)&ob[(size_t)(p0 + ty * 4 + a) * 512 + tx * 4] = *(float4*)o4;
  }
}

// ---------------- beta[idx] = sigmoid( h.Wb[:D] + az.Wb[D:] + bb ) -------------
__global__ __launch_bounds__(256) void k_beta(const float* __restrict__ h,
                                              const float* __restrict__ az,
                                              const float* __restrict__ Wbk,
                                              const float* __restrict__ bbk,
                                              float* __restrict__ beta, int base) {
  const int wid = threadIdx.x >> 6, lane = threadIdx.x & 63;
  const int idx = base + blockIdx.x * 4 + wid; // global (b*N+n)*H + i
  const float* hp = h + (size_t)idx * 128;
  const float* ap = az + (size_t)idx * 128;
  float s = 0.f;
#pragma unroll
  for (int e = 0; e < 2; ++e) {
    int d = lane + e * 64;
    s += hp[d] * Wbk[d] + ap[d] * Wbk[128 + d];
  }
#pragma unroll
  for (int off = 32; off; off >>= 1) s += __shfl_xor(s, off);
  if (lane == 0) beta[idx] = 1.f / (1.f + expf(-(s + bbk[0])));
}

// ---------------- z = beta*h + (1-beta)*az (pointers pre-offset) ---------------
__global__ __launch_bounds__(256) void k_zupd(const float* __restrict__ h,
                                              const float* __restrict__ az,
                                              const float* __restrict__ beta,
                                              float* __restrict__ z) {
  const int i4 = blockIdx.x * 256 + threadIdx.x; // over group's N*H*D/4 float4s
  const float bt = beta[i4 >> 5];
  const float om = 1.f - bt;
  float4 hv = ((const float4*)h)[i4];
  float4 av = ((const float4*)az)[i4];
  float4 zv;
  zv.x = bt * hv.x + om * av.x;
  zv.y = bt * hv.y + om * av.y;
  zv.z = bt * hv.z + om * av.z;
  zv.w = bt * hv.w + om * av.w;
  ((float4*)z)[i4] = zv;
}

// -------- out[n,d] = mean_i z[n,i,d] (- c1 if given); pointers pre-offset ------
__global__ __launch_bounds__(256) void k_headmean(const float* __restrict__ z,
                                                  const float* __restrict__ c1,
                                                  float* __restrict__ out) {
  const int idx = blockIdx.x * 256 + threadIdx.x; // over group's N*D
  const int d = idx & 127, bn = idx >> 7;
  const size_t base = (size_t)bn * 512 + d;
  float v = 0.25f * (z[base] + z[base + 128] + z[base + 256] + z[base + 384]);
  out[idx] = c1 ? (v - c1[idx]) : v;
}

// ---------------- node mean + MLP head ----------------------------------------
__global__ __launch_bounds__(128) void k_final(const float* __restrict__ c,
                                               const float* __restrict__ valid,
                                               const float* __restrict__ Wfc0,
                                               const float* __restrict__ bfc0,
                                               const float* __restrict__ Wfcm,
                                               const float* __restrict__ bfcm,
                                               const float* __restrict__ Wfcl,
                                               const float* __restrict__ bfcl,
                                               float* __restrict__ out) {
  const int b = blockIdx.x, d = threadIdx.x; // 128 threads
  __shared__ float bufA[128], bufB[128], red[128];
  float s = 0.f, vs = 0.f;
  for (int n = 0; n < NN; ++n) {
    float vv = valid[b * NN + n];
    s += c[((size_t)b * NN + n) * 128 + d] * vv;
    vs += vv;
  }
  bufA[d] = s / vs;
  __syncthreads();
  float t = bfc0[d];
  for (int m = 0; m < 128; ++m) t += bufA[m] * Wfc0[m * 128 + d];
  bufB[d] = fmaxf(t, 0.f);
  __syncthreads();
  t = bfcm[d];
  for (int m = 0; m < 128; ++m) t += bufB[m] * Wfcm[m * 128 + d];
  bufA[d] = fmaxf(t, 0.f);
  __syncthreads();
  t = bfcm[128 + d];
  for (int m = 0; m < 128; ++m) t += bufA[m] * Wfcm[128 * 128 + m * 128 + d];
  bufB[d] = fmaxf(t, 0.f);
  __syncthreads();
  red[d] = bufB[d] * Wfcl[d];
  __syncthreads();
  for (int st = 64; st; st >>= 1) {
    if (d < st) red[d] += red[d + st];
    __syncthreads();
  }
  if (d == 0) out[b] = 1.f / (1.f + expf(-(red[0] + bfcl[0])));
}

extern "C" void kernel_launch(void* const* d_in, const int* in_sizes, int n_in,
                              void* d_out, int out_size, void* d_ws, size_t ws_size,
                              hipStream_t stream) {
  (void)in_sizes; (void)n_in; (void)out_size;
  const float* x     = (const float*)d_in[0];
  const float* adj1  = (const float*)d_in[1];
  const float* adj2  = (const float*)d_in[2];
  const float* valid = (const float*)d_in[3];
  const float* Wemb  = (const float*)d_in[4];
  const float* Wh    = (const float*)d_in[5];
  const float* bh    = (const float*)d_in[6];
  const float* We    = (const float*)d_in[7];
  const float* Wb    = (const float*)d_in[8];
  const float* bb    = (const float*)d_in[9];
  const float* Wfc0  = (const float*)d_in[10];
  const float* bfc0  = (const float*)d_in[11];
  const float* Wfcm  = (const float*)d_in[12];
  const float* bfcm  = (const float*)d_in[13];
  const float* Wfcl  = (const float*)d_in[14];
  const float* bfcl  = (const float*)d_in[15];
  float* out = (float*)d_out;

  // ---- workspace layout (adaptive to ws_size) ----
  float* w = (float*)d_ws;
  size_t off = 0;
  float* c     = w + off; off += (size_t)BB * NN * DD;       // 4 MB
  float* c1    = w + off; off += (size_t)BB * NN * DD;       // 4 MB
  float* h     = w + off; off += (size_t)BB * NN * HH * DD;  // 16 MB
  float* g     = w + off; off += (size_t)BB * NN * HH * DD;  // 16 MB
  float* z     = w + off; off += (size_t)BB * NN * HH * DD;  // 16 MB
  float* az    = w + off; off += (size_t)BB * NN * HH * DD;  // 16 MB
  float* beta  = w + off; off += (size_t)BB * NN * HH;       // 128 KB
  const size_t fixedBytes = off * 4;
  const size_t adjTBytes  = 2ull * BB * NN * NN * 2;         // 32 MB (bf16 x2)
  const size_t eGroupBytes = (size_t)HH * NN * NN * 4;       // 16 MB per batch

  int G = 8;
  while (G > 1 && fixedBytes + adjTBytes + (size_t)G * eGroupBytes > ws_size) G >>= 1;
  bool useAdjT = (fixedBytes + adjTBytes + (size_t)G * eGroupBytes <= ws_size);

  unsigned short* adjT1 = (unsigned short*)(w + off);
  unsigned short* adjT2 = adjT1 + (size_t)BB * NN * NN;
  float* e = useAdjT ? (float*)(adjT2 + (size_t)BB * NN * NN) : (w + off);

  if (useAdjT) {
    k_transpose_bf16<<<dim3(32, 32, BB), 256, 0, stream>>>(adj1, adjT1);
    k_transpose_bf16<<<dim3(32, 32, BB), 256, 0, stream>>>(adj2, adjT2);
  }
  // c = x @ W_embede
  k_gemm_k128<<<dim3(128, 2), 256, 0, stream>>>(x, Wemb, nullptr, c, BB * NN, DD);

  for (int k = 0; k < LL; ++k) {
    for (int br = 0; br < 2; ++br) {
      const float* adjcur = (br == 0) ? adj1 : adj2;
      const unsigned short* adjTcur = useAdjT ? ((br == 0) ? adjT1 : adjT2) : nullptr;
      // h = c @ Wh_k + bh_k   -> [B*N, 512]
      k_gemm_k128<<<dim3(128, 8), 256, 0, stream>>>(
          c, Wh + (size_t)k * DD * DD * HH, bh + (size_t)k * DD * HH, h, BB * NN, DD * HH);
      // g = h @ We_k          -> [B*N*H, 128]
      k_gemm_k128<<<dim3(512, 2), 256, 0, stream>>>(
          h, We + (size_t)k * DD * DD, nullptr, g, BB * NN * HH, DD);
      for (int b0 = 0; b0 < BB; b0 += G) {
        const size_t oH = (size_t)b0 * NN * HH * DD; // offset into h/g/z/az
        const size_t oB = (size_t)b0 * NN * HH;      // offset into beta
        const size_t oC = (size_t)b0 * NN * DD;      // offset into c/c1
        k_e<<<dim3(16, 16, G * HH), 256, 0, stream>>>(g, h, e, b0);
        k_soft<<<G * HH * NN, 256, 0, stream>>>(e, adjTcur, adjcur, b0);
        k_az<<<dim3(32, G * HH), 256, 0, stream>>>(e, h, az, b0);
        k_beta<<<G * NN * HH / 4, 256, 0, stream>>>(h, az, Wb + (size_t)k * 2 * DD,
                                                    bb + k, beta, (int)oB);
        k_zupd<<<G * 512, 256, 0, stream>>>(h + oH, az + oH, beta + oB, z + oH);
        for (int t = 2; t <= k + 1; ++t) {
          k_az<<<dim3(32, G * HH), 256, 0, stream>>>(e, z, az, b0);
          k_zupd<<<G * 512, 256, 0, stream>>>(h + oH, az + oH, beta + oB, z + oH);
        }
        // head mean; branch 0 -> c1, branch 1 -> c = mean - c1
        k_headmean<<<G * 512, 256, 0, stream>>>(
            z + oH, (br == 0) ? nullptr : (c1 + oC), ((br == 0) ? c1 : c) + oC);
      }
    }
  }
  k_final<<<BB, 128, 0, stream>>>(c, valid, Wfc0, bfc0, Wfcm, bfcm, Wfcl, bfcl, out);
}

// Round 3
// 3535.162 us; speedup vs baseline: 3.5982x; 3.5982x over previous
//
#include <hip/hip_runtime.h>
#include <hip/hip_bf16.h>

#define BB 8
#define NN 1024
#define DD 128
#define HH 4
#define LL 4

typedef __attribute__((ext_vector_type(8))) short bf16x8;
typedef __attribute__((ext_vector_type(4))) float f32x4;
typedef __attribute__((ext_vector_type(8))) unsigned short u16x8;

__device__ __forceinline__ unsigned short f2bf(float f) {
  union { float f; unsigned int u; } v; v.f = f;
  unsigned int u = v.u;
  unsigned int r = (u + 0x7FFFu + ((u >> 16) & 1u)) >> 16;
  return (unsigned short)r;
}
__device__ __forceinline__ float bf2f(unsigned short s) {
  union { unsigned int u; float f; } v; v.u = ((unsigned int)s) << 16;
  return v.f;
}

// ---------------- adj transpose to bf16: out[b][r][p] = bf16(in[b][p][r]) -----
__global__ __launch_bounds__(256) void k_transpose_bf16(const float* __restrict__ in,
                                                        unsigned short* __restrict__ out) {
  __shared__ float t[32][33];
  int b = blockIdx.z;
  int x0 = blockIdx.x * 32, y0 = blockIdx.y * 32;
  int tx = threadIdx.x & 31, ty = threadIdx.x >> 5; // 32 x 8
  const float* ib = in + (size_t)b * NN * NN;
  unsigned short* ob = out + (size_t)b * NN * NN;
#pragma unroll
  for (int j = 0; j < 32; j += 8)
    t[ty + j][tx] = ib[(size_t)(y0 + ty + j) * NN + x0 + tx];
  __syncthreads();
#pragma unroll
  for (int j = 0; j < 32; j += 8)
    ob[(size_t)(x0 + ty + j) * NN + y0 + tx] = f2bf(t[tx][ty + j]);
}

// ------- K=128 GEMM: C[M,Nn] = A[M,128] @ Bw[128,Nn] (+bias); fp32/bf16 outs ---
__global__ __launch_bounds__(256) void k_gemm_k128(const float* __restrict__ A,
                                                   const float* __restrict__ Bw,
                                                   const float* __restrict__ bias,
                                                   float* __restrict__ C,
                                                   unsigned short* __restrict__ Cbf,
                                                   int M, int Nn) {
  __shared__ __align__(16) float As[32][68]; // [k][m]
  __shared__ __align__(16) float Bs[32][68]; // [k][n]
  const int tm = blockIdx.x * 64, tn = blockIdx.y * 64;
  const int tid = threadIdx.x;
  const int ty = tid >> 4, tx = tid & 15;
  float acc[4][4] = {};
  for (int kc = 0; kc < 128; kc += 32) {
#pragma unroll
    for (int e = 0; e < 8; ++e) {
      int fl = tid + e * 256;
      int r = fl >> 5, k = fl & 31;
      As[k][r] = A[(size_t)(tm + r) * 128 + kc + k];
    }
#pragma unroll
    for (int e = 0; e < 8; ++e) {
      int fl = tid + e * 256;
      int k = fl >> 6, n = fl & 63;
      Bs[k][n] = Bw[(size_t)(kc + k) * Nn + tn + n];
    }
    __syncthreads();
#pragma unroll
    for (int kk = 0; kk < 32; ++kk) {
      float a4[4], b4[4];
      *(float4*)a4 = *(const float4*)&As[kk][ty * 4];
      *(float4*)b4 = *(const float4*)&Bs[kk][tx * 4];
#pragma unroll
      for (int i = 0; i < 4; ++i)
#pragma unroll
        for (int j = 0; j < 4; ++j) acc[i][j] += a4[i] * b4[j];
    }
    __syncthreads();
  }
#pragma unroll
  for (int i = 0; i < 4; ++i) {
    float o4[4];
#pragma unroll
    for (int j = 0; j < 4; ++j) {
      float v = acc[i][j];
      if (bias) v += bias[tn + tx * 4 + j];
      o4[j] = v;
    }
    size_t base = (size_t)(tm + ty * 4 + i) * Nn + tn + tx * 4;
    if (C) *(float4*)&C[base] = *(float4*)o4;
    if (Cbf) {
      unsigned int lo = (unsigned int)f2bf(o4[0]) | ((unsigned int)f2bf(o4[1]) << 16);
      unsigned int hi = (unsigned int)f2bf(o4[2]) | ((unsigned int)f2bf(o4[3]) << 16);
      uint2 pv; pv.x = lo; pv.y = hi;
      *(uint2*)&Cbf[base] = pv;
    }
  }
}

// ------- E tile via MFMA: e[p][r] = g[p]·h[r] + h[p]·g[r]  (NT, bf16 in) -------
__global__ __launch_bounds__(256) void k_e_mfma(const unsigned short* __restrict__ g,
                                                const unsigned short* __restrict__ h,
                                                float* __restrict__ e, int b0) {
  const int tp = blockIdx.x, tr = blockIdx.y;
  if (tp > tr) return; // symmetric: upper-triangular tile pairs only
  const int gi = blockIdx.z;
  const int b = b0 + (gi >> 2), i = gi & 3;
  const int p0 = tp * 64, r0 = tr * 64;
  const bool diag = (tp == tr);
  __shared__ __align__(16) char lds[65536];
  unsigned short* S = (unsigned short*)lds;
  const int tid = threadIdx.x;
  const unsigned short* gb = g + (size_t)b * NN * 512 + i * 128;
  const unsigned short* hb = h + (size_t)b * NN * 512 + i * 128;
  // stage tiles: t=0 Gp, 1 Hp, 2 Gr, 3 Hr; row=node-local, 16 chunks of 16B,
  // chunk index XOR-swizzled by (row&7) to kill the 128-bf16-row bank conflict.
  const int ntiles = diag ? 2 : 4;
  for (int s = tid; s < ntiles * 1024; s += 256) {
    int t = s >> 10, row = (s >> 4) & 63, ch = s & 15;
    const unsigned short* src = (t & 1) ? hb : gb;
    int node = ((t >> 1) ? r0 : p0) + row;
    uint4 v = *(const uint4*)(src + (size_t)node * 512 + ch * 8);
    *(uint4*)(S + t * 8192 + row * 128 + ((ch ^ (row & 7)) * 8)) = v;
  }
  __syncthreads();
  const int wave = tid >> 6, lane = tid & 63;
  const int l15 = lane & 15, kq = lane >> 4;
  const int mrow = wave * 16 + l15;
  const int GrB = diag ? 0 : 16384, HrB = diag ? 8192 : 24576;
  f32x4 acc[4] = {};
#define LDF(base, row, kk) \
  (*(const bf16x8*)(S + (base) + (row) * 128 + ((((kk) * 4 + kq) ^ ((row) & 7)) * 8)))
#pragma unroll
  for (int kk = 0; kk < 4; ++kk) {
    bf16x8 gA = LDF(0, mrow, kk);
    bf16x8 hA = LDF(8192, mrow, kk);
#pragma unroll
    for (int cb = 0; cb < 4; ++cb) {
      int nrow = cb * 16 + l15;
      bf16x8 hB = LDF(HrB, nrow, kk);
      bf16x8 gB = LDF(GrB, nrow, kk);
      acc[cb] = __builtin_amdgcn_mfma_f32_16x16x32_bf16(gA, hB, acc[cb], 0, 0, 0);
      acc[cb] = __builtin_amdgcn_mfma_f32_16x16x32_bf16(hA, gB, acc[cb], 0, 0, 0);
    }
  }
#undef LDF
  __syncthreads();
  // re-tile through LDS so both orientations store as coalesced float4
  float* eN = (float*)lds;           // [64][68]
  float* eT = eN + 64 * 68;          // [64][68]
#pragma unroll
  for (int cb = 0; cb < 4; ++cb)
#pragma unroll
    for (int rg = 0; rg < 4; ++rg) {
      int pl = wave * 16 + kq * 4 + rg;  // D row = (lane>>4)*4 + reg
      int rl = cb * 16 + l15;            // D col = lane&15
      float v = acc[cb][rg];
      eN[pl * 68 + rl] = v;
      if (!diag) eT[rl * 68 + pl] = v;
    }
  __syncthreads();
  float* eb = e + (size_t)gi * NN * NN;
  const int ty = tid >> 4, tx = tid & 15;
#pragma unroll
  for (int a2 = 0; a2 < 4; ++a2) {
    float4 v = *(float4*)&eN[(ty * 4 + a2) * 68 + tx * 4];
    *(float4*)&eb[(size_t)(p0 + ty * 4 + a2) * NN + r0 + tx * 4] = v;
  }
  if (!diag) {
#pragma unroll
    for (int a2 = 0; a2 < 4; ++a2) {
      float4 v = *(float4*)&eT[(ty * 4 + a2) * 68 + tx * 4];
      *(float4*)&eb[(size_t)(r0 + ty * 4 + a2) * NN + p0 + tx * 4] = v;
    }
  }
}

// --------- softmax over p per column r, * adj; writes bf16 attT overlaid in e --
__global__ __launch_bounds__(256) void k_soft(float* __restrict__ e,
                                              const unsigned short* __restrict__ adjT,
                                              const float* __restrict__ adj, int b0) {
  const int col = blockIdx.x;            // local (gi)*N + r
  const int r = col & (NN - 1);
  const int gi = col >> 10;
  const int b = b0 + (gi >> 2);
  const float* erow = e + (size_t)col * NN;
  const unsigned short* atrow = adjT ? adjT + ((size_t)b * NN + r) * NN : nullptr;
  const float* acol = adj + (size_t)b * NN * NN + r; // adj[b][p][r], stride NN
  const int tid = threadIdx.x;
  float sv[4], av[4], ex[4];
  float mx = -1e30f;
#pragma unroll
  for (int j = 0; j < 4; ++j) {
    int p = tid + j * 256;
    float a = atrow ? bf2f(atrow[p]) : acol[(size_t)p * NN];
    av[j] = a;
    float ev = erow[p];
    float s = (a > 0.f) ? ev : 0.f;
    sv[j] = s;
    mx = fmaxf(mx, s);
  }
  __shared__ float sm[4], ssum[4];
  const int wid = tid >> 6, lane = tid & 63;
#pragma unroll
  for (int off = 32; off; off >>= 1) mx = fmaxf(mx, __shfl_xor(mx, off));
  if (lane == 0) sm[wid] = mx;
  __syncthreads();
  mx = fmaxf(fmaxf(sm[0], sm[1]), fmaxf(sm[2], sm[3]));
  float psum = 0.f;
#pragma unroll
  for (int j = 0; j < 4; ++j) {
    ex[j] = expf(sv[j] - mx); // masked: exp(0-mx) — counts in denominator
    psum += ex[j];
  }
#pragma unroll
  for (int off = 32; off; off >>= 1) psum += __shfl_xor(psum, off);
  if (lane == 0) ssum[wid] = psum;
  __syncthreads();
  float inv = 1.f / (ssum[0] + ssum[1] + ssum[2] + ssum[3]);
  unsigned short* attrow = (unsigned short*)erow; // overlay: first half of row
#pragma unroll
  for (int j = 0; j < 4; ++j) {
    int p = tid + j * 256;
    float att = (av[j] > 0.f) ? ex[j] * inv * av[j] : 0.f;
    attrow[p] = f2bf(att);
  }
}

// ---- az[p,q] = relu( sum_r attT[r,p] * z[r,q] ) via MFMA (transpose-staged) ---
__global__ __launch_bounds__(256) void k_az_mfma(const float* __restrict__ eAtt,
                                                 const unsigned short* __restrict__ zbf,
                                                 float* __restrict__ azout, int b0) {
  const int pblk = blockIdx.x * 32;
  const int gi = blockIdx.y;
  const int b = b0 + (gi >> 2), i = gi & 3;
  __shared__ __align__(16) char Ab[4096];   // A[32p][64r] bf16, 128B rows, swizzled
  __shared__ __align__(16) char Bb[16384];  // B[128q][64r] bf16, 128B rows, swizzled
  const unsigned short* att = (const unsigned short*)eAtt;
  const unsigned short* zb = zbf + (size_t)b * NN * 512 + i * 128;
  const int tid = threadIdx.x;
  const int lane = tid & 63;
  const int wave = tid >> 6, wp = wave & 1, wq = wave >> 1;
  const int l15 = lane & 15, kq = lane >> 4;
  f32x4 acc[4] = {};
  for (int rc = 0; rc < NN; rc += 64) {
    __syncthreads();
    if (tid < 64) { // stage A: attT rows -> [p][r], packed b64 transpose writes
      const int ps = (tid & 3) * 8;
      const int rs = (tid >> 2) * 4;
      u16x8 L[4];
#pragma unroll
      for (int ri = 0; ri < 4; ++ri)
        L[ri] = *(const u16x8*)(att + ((size_t)gi * NN + rc + rs + ri) * 2048 + pblk + ps);
#pragma unroll
      for (int j = 0; j < 8; ++j) {
        int p = ps + j;
        uint2 pv;
        pv.x = (unsigned int)(unsigned short)L[0][j] | ((unsigned int)(unsigned short)L[1][j] << 16);
        pv.y = (unsigned int)(unsigned short)L[2][j] | ((unsigned int)(unsigned short)L[3][j] << 16);
        *(uint2*)(Ab + ((p * 128 + rs * 2) ^ ((p & 7) << 4))) = pv;
      }
    }
    { // stage B: z rows -> [q][r]
      const int qs = (tid & 15) * 8;
      const int rs = (tid >> 4) * 4;
      u16x8 L[4];
#pragma unroll
      for (int ri = 0; ri < 4; ++ri)
        L[ri] = *(const u16x8*)(zb + (size_t)(rc + rs + ri) * 512 + qs);
#pragma unroll
      for (int j = 0; j < 8; ++j) {
        int q = qs + j;
        uint2 pv;
        pv.x = (unsigned int)(unsigned short)L[0][j] | ((unsigned int)(unsigned short)L[1][j] << 16);
        pv.y = (unsigned int)(unsigned short)L[2][j] | ((unsigned int)(unsigned short)L[3][j] << 16);
        *(uint2*)(Bb + ((q * 128 + rs * 2) ^ ((q & 7) << 4))) = pv;
      }
    }
    __syncthreads();
#pragma unroll
    for (int kk = 0; kk < 2; ++kk) {
      int ml = wp * 16 + l15;
      bf16x8 a = *(const bf16x8*)(Ab + ((ml * 128 + kk * 64 + kq * 16) ^ ((ml & 7) << 4)));
#pragma unroll
      for (int cb = 0; cb < 4; ++cb) {
        int nl = wq * 64 + cb * 16 + l15;
        bf16x8 bf = *(const bf16x8*)(Bb + ((nl * 128 + kk * 64 + kq * 16) ^ ((nl & 7) << 4)));
        acc[cb] = __builtin_amdgcn_mfma_f32_16x16x32_bf16(a, bf, acc[cb], 0, 0, 0);
      }
    }
  }
  float* ob = azout + (size_t)b * NN * 512 + i * 128;
#pragma unroll
  for (int cb = 0; cb < 4; ++cb)
#pragma unroll
    for (int rg = 0; rg < 4; ++rg) {
      int p = pblk + wp * 16 + kq * 4 + rg;
      int q = wq * 64 + cb * 16 + l15;
      ob[(size_t)p * 512 + q] = fmaxf(acc[cb][rg], 0.f);
    }
}

// ---------------- beta[idx] = sigmoid( h.Wb[:D] + az.Wb[D:] + bb ) -------------
__global__ __launch_bounds__(256) void k_beta(const float* __restrict__ h,
                                              const float* __restrict__ az,
                                              const float* __restrict__ Wbk,
                                              const float* __restrict__ bbk,
                                              float* __restrict__ beta, int base) {
  const int wid = threadIdx.x >> 6, lane = threadIdx.x & 63;
  const int idx = base + blockIdx.x * 4 + wid; // global (b*N+n)*H + i
  const float* hp = h + (size_t)idx * 128;
  const float* ap = az + (size_t)idx * 128;
  float s = 0.f;
#pragma unroll
  for (int e = 0; e < 2; ++e) {
    int d = lane + e * 64;
    s += hp[d] * Wbk[d] + ap[d] * Wbk[128 + d];
  }
#pragma unroll
  for (int off = 32; off; off >>= 1) s += __shfl_xor(s, off);
  if (lane == 0) beta[idx] = 1.f / (1.f + expf(-(s + bbk[0])));
}

// --------- z = beta*h + (1-beta)*az  (fp32 + bf16 outs; pointers pre-offset) ---
__global__ __launch_bounds__(256) void k_zupd(const float* __restrict__ h,
                                              const float* __restrict__ az,
                                              const float* __restrict__ beta,
                                              float* __restrict__ z,
                                              unsigned short* __restrict__ zbf) {
  const int i4 = blockIdx.x * 256 + threadIdx.x; // over group's N*H*D/4 float4s
  const float bt = beta[i4 >> 5];
  const float om = 1.f - bt;
  float4 hv = ((const float4*)h)[i4];
  float4 av = ((const float4*)az)[i4];
  float4 zv;
  zv.x = bt * hv.x + om * av.x;
  zv.y = bt * hv.y + om * av.y;
  zv.z = bt * hv.z + om * av.z;
  zv.w = bt * hv.w + om * av.w;
  ((float4*)z)[i4] = zv;
  uint2 pv;
  pv.x = (unsigned int)f2bf(zv.x) | ((unsigned int)f2bf(zv.y) << 16);
  pv.y = (unsigned int)f2bf(zv.z) | ((unsigned int)f2bf(zv.w) << 16);
  *(uint2*)(zbf + (size_t)i4 * 4) = pv;
}

// -------- out[n,d] = mean_i z[n,i,d] (- c1 if given); pointers pre-offset ------
__global__ __launch_bounds__(256) void k_headmean(const float* __restrict__ z,
                                                  const float* __restrict__ c1,
                                                  float* __restrict__ out) {
  const int idx = blockIdx.x * 256 + threadIdx.x; // over group's N*D
  const int d = idx & 127, bn = idx >> 7;
  const size_t base = (size_t)bn * 512 + d;
  float v = 0.25f * (z[base] + z[base + 128] + z[base + 256] + z[base + 384]);
  out[idx] = c1 ? (v - c1[idx]) : v;
}

// ---------------- node mean + MLP head ----------------------------------------
__global__ __launch_bounds__(128) void k_final(const float* __restrict__ c,
                                               const float* __restrict__ valid,
                                               const float* __restrict__ Wfc0,
                                               const float* __restrict__ bfc0,
                                               const float* __restrict__ Wfcm,
                                               const float* __restrict__ bfcm,
                                               const float* __restrict__ Wfcl,
                                               const float* __restrict__ bfcl,
                                               float* __restrict__ out) {
  const int b = blockIdx.x, d = threadIdx.x; // 128 threads
  __shared__ float bufA[128], bufB[128], red[128];
  float s = 0.f, vs = 0.f;
  for (int n = 0; n < NN; ++n) {
    float vv = valid[b * NN + n];
    s += c[((size_t)b * NN + n) * 128 + d] * vv;
    vs += vv;
  }
  bufA[d] = s / vs;
  __syncthreads();
  float t = bfc0[d];
  for (int m = 0; m < 128; ++m) t += bufA[m] * Wfc0[m * 128 + d];
  bufB[d] = fmaxf(t, 0.f);
  __syncthreads();
  t = bfcm[d];
  for (int m = 0; m < 128; ++m) t += bufB[m] * Wfcm[m * 128 + d];
  bufA[d] = fmaxf(t, 0.f);
  __syncthreads();
  t = bfcm[128 + d];
  for (int m = 0; m < 128; ++m) t += bufA[m] * Wfcm[128 * 128 + m * 128 + d];
  bufB[d] = fmaxf(t, 0.f);
  __syncthreads();
  red[d] = bufB[d] * Wfcl[d];
  __syncthreads();
  for (int st = 64; st; st >>= 1) {
    if (d < st) red[d] += red[d + st];
    __syncthreads();
  }
  if (d == 0) out[b] = 1.f / (1.f + expf(-(red[0] + bfcl[0])));
}

extern "C" void kernel_launch(void* const* d_in, const int* in_sizes, int n_in,
                              void* d_out, int out_size, void* d_ws, size_t ws_size,
                              hipStream_t stream) {
  (void)in_sizes; (void)n_in; (void)out_size;
  const float* x     = (const float*)d_in[0];
  const float* adj1  = (const float*)d_in[1];
  const float* adj2  = (const float*)d_in[2];
  const float* valid = (const float*)d_in[3];
  const float* Wemb  = (const float*)d_in[4];
  const float* Wh    = (const float*)d_in[5];
  const float* bh    = (const float*)d_in[6];
  const float* We    = (const float*)d_in[7];
  const float* Wb    = (const float*)d_in[8];
  const float* bb    = (const float*)d_in[9];
  const float* Wfc0  = (const float*)d_in[10];
  const float* bfc0  = (const float*)d_in[11];
  const float* Wfcm  = (const float*)d_in[12];
  const float* bfcm  = (const float*)d_in[13];
  const float* Wfcl  = (const float*)d_in[14];
  const float* bfcl  = (const float*)d_in[15];
  float* out = (float*)d_out;

  // ---- workspace layout (adaptive to ws_size) ----
  float* w = (float*)d_ws;
  size_t off = 0;
  float* c     = w + off; off += (size_t)BB * NN * DD;       // 4 MB
  float* c1    = w + off; off += (size_t)BB * NN * DD;       // 4 MB
  float* h     = w + off; off += (size_t)BB * NN * HH * DD;  // 16 MB
  float* z     = w + off; off += (size_t)BB * NN * HH * DD;  // 16 MB
  float* az    = w + off; off += (size_t)BB * NN * HH * DD;  // 16 MB
  float* beta  = w + off; off += (size_t)BB * NN * HH;       // 128 KB
  unsigned short* h_bf = (unsigned short*)(w + off); off += (size_t)BB * NN * HH * DD / 2; // 8 MB
  unsigned short* g_bf = (unsigned short*)(w + off); off += (size_t)BB * NN * HH * DD / 2; // 8 MB
  unsigned short* z_bf = (unsigned short*)(w + off); off += (size_t)BB * NN * HH * DD / 2; // 8 MB
  const size_t fixedBytes = off * 4;
  const size_t adjTBytes  = 2ull * BB * NN * NN * 2;         // 32 MB (bf16 x2)
  const size_t eGroupBytes = (size_t)HH * NN * NN * 4;       // 16 MB per batch

  int G = 8;
  while (G > 1 && fixedBytes + adjTBytes + (size_t)G * eGroupBytes > ws_size) G >>= 1;
  bool useAdjT = (fixedBytes + adjTBytes + (size_t)G * eGroupBytes <= ws_size);

  unsigned short* adjT1 = (unsigned short*)(w + off);
  unsigned short* adjT2 = adjT1 + (size_t)BB * NN * NN;
  float* e = useAdjT ? (float*)(adjT2 + (size_t)BB * NN * NN) : (w + off);

  if (useAdjT) {
    k_transpose_bf16<<<dim3(32, 32, BB), 256, 0, stream>>>(adj1, adjT1);
    k_transpose_bf16<<<dim3(32, 32, BB), 256, 0, stream>>>(adj2, adjT2);
  }
  // c = x @ W_embede
  k_gemm_k128<<<dim3(128, 2), 256, 0, stream>>>(x, Wemb, nullptr, c, nullptr, BB * NN, DD);

  for (int k = 0; k < LL; ++k) {
    for (int br = 0; br < 2; ++br) {
      const float* adjcur = (br == 0) ? adj1 : adj2;
      const unsigned short* adjTcur = useAdjT ? ((br == 0) ? adjT1 : adjT2) : nullptr;
      // h = c @ Wh_k + bh_k   -> [B*N, 512] fp32 + bf16
      k_gemm_k128<<<dim3(128, 8), 256, 0, stream>>>(
          c, Wh + (size_t)k * DD * DD * HH, bh + (size_t)k * DD * HH, h, h_bf, BB * NN, DD * HH);
      // g = h @ We_k          -> [B*N*H, 128] bf16 only
      k_gemm_k128<<<dim3(512, 2), 256, 0, stream>>>(
          h, We + (size_t)k * DD * DD, nullptr, nullptr, g_bf, BB * NN * HH, DD);
      for (int b0 = 0; b0 < BB; b0 += G) {
        const size_t oH = (size_t)b0 * NN * HH * DD; // offset into h/z/az
        const size_t oB = (size_t)b0 * NN * HH;      // offset into beta
        const size_t oC = (size_t)b0 * NN * DD;      // offset into c/c1
        k_e_mfma<<<dim3(16, 16, G * HH), 256, 0, stream>>>(g_bf, h_bf, e, b0);
        k_soft<<<G * HH * NN, 256, 0, stream>>>(e, adjTcur, adjcur, b0);
        k_az_mfma<<<dim3(32, G * HH), 256, 0, stream>>>(e, h_bf, az, b0);
        k_beta<<<G * NN * HH / 4, 256, 0, stream>>>(h, az, Wb + (size_t)k * 2 * DD,
                                                    bb + k, beta, (int)oB);
        k_zupd<<<G * 512, 256, 0, stream>>>(h + oH, az + oH, beta + oB, z + oH, z_bf + oH);
        for (int t = 2; t <= k + 1; ++t) {
          k_az_mfma<<<dim3(32, G * HH), 256, 0, stream>>>(e, z_bf, az, b0);
          k_zupd<<<G * 512, 256, 0, stream>>>(h + oH, az + oH, beta + oB, z + oH, z_bf + oH);
        }
        // head mean; branch 0 -> c1, branch 1 -> c = mean - c1
        k_headmean<<<G * 512, 256, 0, stream>>>(
            z + oH, (br == 0) ? nullptr : (c1 + oC), ((br == 0) ? c1 : c) + oC);
      }
    }
  }
  k_final<<<BB, 128, 0, stream>>>(c, valid, Wfc0, bfc0, Wfcm, bfcm, Wfcl, bfcl, out);
}

// Round 4
// 2774.128 us; speedup vs baseline: 4.5853x; 1.2743x over previous
//
#include <hip/hip_runtime.h>
#include <hip/hip_bf16.h>

#define BB 8
#define NN 1024
#define DD 128
#define HH 4
#define LL 4

typedef __attribute__((ext_vector_type(8))) short bf16x8;
typedef __attribute__((ext_vector_type(4))) float f32x4;
typedef __attribute__((ext_vector_type(8))) unsigned short u16x8;

__device__ __forceinline__ unsigned short f2bf(float f) {
  union { float f; unsigned int u; } v; v.f = f;
  unsigned int u = v.u;
  return (unsigned short)((u + 0x7FFFu + ((u >> 16) & 1u)) >> 16);
}
__device__ __forceinline__ float bf2f(unsigned short s) {
  union { unsigned int u; float f; } v; v.u = ((unsigned int)s) << 16;
  return v.f;
}
__device__ __forceinline__ unsigned short f2h(float f) {
  union { _Float16 h; unsigned short u; } v; v.h = (_Float16)f;
  return v.u;
}
__device__ __forceinline__ float h2f(unsigned short u) {
  union { unsigned short u; _Float16 h; } v; v.u = u;
  return (float)v.h;
}

// ---------------- adj transpose to bf16: out[b][r][p] = bf16(in[b][p][r]) -----
__global__ __launch_bounds__(256) void k_transpose_bf16(const float* __restrict__ in,
                                                        unsigned short* __restrict__ out) {
  __shared__ float t[32][33];
  int b = blockIdx.z;
  int x0 = blockIdx.x * 32, y0 = blockIdx.y * 32;
  int tx = threadIdx.x & 31, ty = threadIdx.x >> 5; // 32 x 8
  const float* ib = in + (size_t)b * NN * NN;
  unsigned short* ob = out + (size_t)b * NN * NN;
#pragma unroll
  for (int j = 0; j < 32; j += 8)
    t[ty + j][tx] = ib[(size_t)(y0 + ty + j) * NN + x0 + tx];
  __syncthreads();
#pragma unroll
  for (int j = 0; j < 32; j += 8)
    ob[(size_t)(x0 + ty + j) * NN + y0 + tx] = f2bf(t[tx][ty + j]);
}

// ------- weight transpose: in [nm][128][Nn] fp32 -> out [nm][Nn][128] bf16 -----
__global__ __launch_bounds__(256) void k_wtrans(const float* __restrict__ in,
                                                unsigned short* __restrict__ out, int Nn) {
  __shared__ float t[32][33];
  int m = blockIdx.z;
  const float* ib = in + (size_t)m * 128 * Nn;
  unsigned short* ob = out + (size_t)m * Nn * 128;
  int k0 = blockIdx.x * 32, n0 = blockIdx.y * 32;
  int tx = threadIdx.x & 31, ty = threadIdx.x >> 5;
#pragma unroll
  for (int j = 0; j < 32; j += 8)
    t[ty + j][tx] = ib[(size_t)(k0 + ty + j) * Nn + n0 + tx];
  __syncthreads();
#pragma unroll
  for (int j = 0; j < 32; j += 8)
    ob[(size_t)(n0 + ty + j) * 128 + k0 + tx] = f2bf(t[tx][ty + j]);
}

// ------- SIMT K=128 GEMM (embed only): C = A[M,128] @ Bw[128,Nn]; fp32+bf16 ----
__global__ __launch_bounds__(256) void k_gemm_k128(const float* __restrict__ A,
                                                   const float* __restrict__ Bw,
                                                   float* __restrict__ C,
                                                   unsigned short* __restrict__ Cbf,
                                                   int M, int Nn) {
  __shared__ __align__(16) float As[32][68];
  __shared__ __align__(16) float Bs[32][68];
  const int tm = blockIdx.x * 64, tn = blockIdx.y * 64;
  const int tid = threadIdx.x;
  const int ty = tid >> 4, tx = tid & 15;
  float acc[4][4] = {};
  for (int kc = 0; kc < 128; kc += 32) {
#pragma unroll
    for (int e = 0; e < 8; ++e) {
      int fl = tid + e * 256;
      int r = fl >> 5, k = fl & 31;
      As[k][r] = A[(size_t)(tm + r) * 128 + kc + k];
    }
#pragma unroll
    for (int e = 0; e < 8; ++e) {
      int fl = tid + e * 256;
      int k = fl >> 6, n = fl & 63;
      Bs[k][n] = Bw[(size_t)(kc + k) * Nn + tn + n];
    }
    __syncthreads();
#pragma unroll
    for (int kk = 0; kk < 32; ++kk) {
      float a4[4], b4[4];
      *(float4*)a4 = *(const float4*)&As[kk][ty * 4];
      *(float4*)b4 = *(const float4*)&Bs[kk][tx * 4];
#pragma unroll
      for (int i = 0; i < 4; ++i)
#pragma unroll
        for (int j = 0; j < 4; ++j) acc[i][j] += a4[i] * b4[j];
    }
    __syncthreads();
  }
#pragma unroll
  for (int i = 0; i < 4; ++i) {
    size_t base = (size_t)(tm + ty * 4 + i) * Nn + tn + tx * 4;
    *(float4*)&C[base] = *(float4*)acc[i];
    uint2 pv;
    pv.x = (unsigned int)f2bf(acc[i][0]) | ((unsigned int)f2bf(acc[i][1]) << 16);
    pv.y = (unsigned int)f2bf(acc[i][2]) | ((unsigned int)f2bf(acc[i][3]) << 16);
    *(uint2*)&Cbf[base] = pv;
  }
}

// ------- MFMA NT GEMM, K=128: out[M,Nn](bf16) = A[M,128](bf16) @ Bt[Nn,128]^T --
__global__ __launch_bounds__(256) void k_gemm_nt(const unsigned short* __restrict__ A,
                                                 const unsigned short* __restrict__ Bt,
                                                 const float* __restrict__ bias,
                                                 unsigned short* __restrict__ outp,
                                                 int Nn) {
  const int m0 = blockIdx.x * 64, n0 = blockIdx.y * 64;
  const int tid = threadIdx.x;
  const int wave = tid >> 6, lane = tid & 63;
  const int l15 = lane & 15, kq = lane >> 4;
  __shared__ __align__(16) unsigned short O[64][72];
  const unsigned short* aP = A + (size_t)(m0 + wave * 16 + l15) * 128;
  f32x4 acc[4] = {};
#pragma unroll
  for (int kk = 0; kk < 4; ++kk) {
    bf16x8 aF = *(const bf16x8*)(aP + (kk * 4 + kq) * 8);
#pragma unroll
    for (int cb = 0; cb < 4; ++cb) {
      bf16x8 bF = *(const bf16x8*)(Bt + (size_t)(n0 + cb * 16 + l15) * 128 + (kk * 4 + kq) * 8);
      acc[cb] = __builtin_amdgcn_mfma_f32_16x16x32_bf16(aF, bF, acc[cb], 0, 0, 0);
    }
  }
#pragma unroll
  for (int cb = 0; cb < 4; ++cb) {
    float bv = bias ? bias[n0 + cb * 16 + l15] : 0.f;
#pragma unroll
    for (int rg = 0; rg < 4; ++rg)
      O[wave * 16 + kq * 4 + rg][cb * 16 + l15] = f2bf(acc[cb][rg] + bv);
  }
  __syncthreads();
#pragma unroll
  for (int it = 0; it < 2; ++it) {
    int row = (tid >> 3) + it * 32, ch = tid & 7;
    *(uint4*)&outp[(size_t)(m0 + row) * Nn + n0 + ch * 8] = *(uint4*)&O[row][ch * 8];
  }
}

// ------- E tile via MFMA -> fp16: e[p][r] = g[p]·h[r] + h[p]·g[r] (symmetric) --
// A-frags direct from global; B tiles (r-side) staged in 32KB swizzled LDS.
__global__ __launch_bounds__(256) void k_e_mfma(const unsigned short* __restrict__ g,
                                                const unsigned short* __restrict__ h,
                                                unsigned short* __restrict__ e, int b0) {
  const int tp = blockIdx.x, tr = blockIdx.y;
  if (tp > tr) return;
  const int gi = blockIdx.z;
  const int b = b0 + (gi >> 2), i = gi & 3;
  const int p0 = tp * 64, r0 = tr * 64;
  const bool diag = (tp == tr);
  __shared__ __align__(16) char lds[32768];
  const int tid = threadIdx.x;
  const unsigned short* gb = g + (size_t)b * NN * 512 + i * 128;
  const unsigned short* hb = h + (size_t)b * NN * 512 + i * 128;
  // stage B tiles: [0]=Gr, [16384]=Hr ; row-local 256B, chunk^(row&7) swizzle
#pragma unroll
  for (int e2 = 0; e2 < 8; ++e2) {
    int fl = tid + e2 * 256;        // 0..2047
    int t = fl >> 10, rem = fl & 1023;
    int row = rem >> 4, ch = rem & 15;
    const unsigned short* src = t ? hb : gb;
    uint4 v = *(const uint4*)(src + (size_t)(r0 + row) * 512 + ch * 8);
    *(uint4*)(lds + t * 16384 + row * 256 + ((ch ^ (row & 7)) * 16)) = v;
  }
  __syncthreads();
  const int wave = tid >> 6, lane = tid & 63;
  const int l15 = lane & 15, kq = lane >> 4;
  const unsigned short* aG = gb + (size_t)(p0 + wave * 16 + l15) * 512;
  const unsigned short* aH = hb + (size_t)(p0 + wave * 16 + l15) * 512;
  f32x4 acc[4] = {};
#pragma unroll
  for (int kk = 0; kk < 4; ++kk) {
    bf16x8 gA = *(const bf16x8*)(aG + (kk * 4 + kq) * 8);
    bf16x8 hA = *(const bf16x8*)(aH + (kk * 4 + kq) * 8);
#pragma unroll
    for (int cb = 0; cb < 4; ++cb) {
      int row = cb * 16 + l15;
      int chs = ((kk * 4 + kq) ^ (row & 7)) * 16;
      bf16x8 gB = *(const bf16x8*)(lds + row * 256 + chs);
      bf16x8 hB = *(const bf16x8*)(lds + 16384 + row * 256 + chs);
      acc[cb] = __builtin_amdgcn_mfma_f32_16x16x32_bf16(gA, hB, acc[cb], 0, 0, 0);
      acc[cb] = __builtin_amdgcn_mfma_f32_16x16x32_bf16(hA, gB, acc[cb], 0, 0, 0);
    }
  }
  __syncthreads(); // B tiles fully consumed; reuse LDS for retile
  unsigned short* eN = (unsigned short*)lds;   // [64][72] fp16
  unsigned short* eT = eN + 64 * 72;
#pragma unroll
  for (int cb = 0; cb < 4; ++cb)
#pragma unroll
    for (int rg = 0; rg < 4; ++rg) {
      int pl = wave * 16 + kq * 4 + rg;
      int rl = cb * 16 + l15;
      unsigned short v = f2h(acc[cb][rg]);
      eN[pl * 72 + rl] = v;
      if (!diag) eT[rl * 72 + pl] = v;
    }
  __syncthreads();
  unsigned short* eb = e + (size_t)gi * NN * NN;
#pragma unroll
  for (int it = 0; it < 2; ++it) {
    int row = (tid >> 3) + it * 32, ch = tid & 7;
    *(uint4*)&eb[(size_t)(p0 + row) * NN + r0 + ch * 8] = *(uint4*)&eN[row * 72 + ch * 8];
    if (!diag)
      *(uint4*)&eb[(size_t)(r0 + row) * NN + p0 + ch * 8] = *(uint4*)&eT[row * 72 + ch * 8];
  }
}

// --------- softmax over p per column r, * adj; att bf16 overwrites e in place --
// e row (gi,r,:) fp16 == E column r by symmetry; att[p,r] written to same slots.
__global__ __launch_bounds__(256) void k_soft(unsigned short* __restrict__ e,
                                              const unsigned short* __restrict__ adjT,
                                              const float* __restrict__ adj, int b0) {
  const int col = blockIdx.x;            // local gi*N + r
  const int r = col & (NN - 1);
  const int gi = col >> 10;
  const int b = b0 + (gi >> 2);
  unsigned short* erow = e + (size_t)col * NN;
  const unsigned short* atrow = adjT ? adjT + ((size_t)b * NN + r) * NN : nullptr;
  const float* acol = adj + (size_t)b * NN * NN + r;
  const int tid = threadIdx.x;
  float sv[4], av[4], ex[4];
  float mx = -1e30f;
#pragma unroll
  for (int j = 0; j < 4; ++j) {
    int p = tid + j * 256;
    float a = atrow ? bf2f(atrow[p]) : acol[(size_t)p * NN];
    av[j] = a;
    float s = (a > 0.f) ? h2f(erow[p]) : 0.f;
    sv[j] = s;
    mx = fmaxf(mx, s);
  }
  __shared__ float sm[4], ssum[4];
  const int wid = tid >> 6, lane = tid & 63;
#pragma unroll
  for (int off = 32; off; off >>= 1) mx = fmaxf(mx, __shfl_xor(mx, off));
  if (lane == 0) sm[wid] = mx;
  __syncthreads();
  mx = fmaxf(fmaxf(sm[0], sm[1]), fmaxf(sm[2], sm[3]));
  float psum = 0.f;
#pragma unroll
  for (int j = 0; j < 4; ++j) {
    ex[j] = expf(sv[j] - mx); // masked entries contribute exp(0-mx)
    psum += ex[j];
  }
#pragma unroll
  for (int off = 32; off; off >>= 1) psum += __shfl_xor(psum, off);
  if (lane == 0) ssum[wid] = psum;
  __syncthreads();
  float inv = 1.f / (ssum[0] + ssum[1] + ssum[2] + ssum[3]);
#pragma unroll
  for (int j = 0; j < 4; ++j) {
    int p = tid + j * 256;
    float att = (av[j] > 0.f) ? ex[j] * inv * av[j] : 0.f;
    erow[p] = f2bf(att); // in-place: each element read before written by same thread
  }
}

// ---- az/hop kernel: acc[p,q] = sum_r att[r-row][p] * z[r,q]  (MFMA, bf16) -----
// mode az0 (h==null): out = relu(acc) -> az
// mode hop (h!=null): out = beta*h + (1-beta)*relu(acc) -> z_out
__global__ __launch_bounds__(256) void k_az_mfma(const unsigned short* __restrict__ att,
                                                 const unsigned short* __restrict__ zin,
                                                 const unsigned short* __restrict__ h,
                                                 const float* __restrict__ beta,
                                                 unsigned short* __restrict__ outp,
                                                 int b0) {
  const int pblk = blockIdx.x * 32;
  const int gi = blockIdx.y;
  const int b = b0 + (gi >> 2), i = gi & 3;
  __shared__ __align__(16) char Ab[4096];   // [32p][64r] bf16 swizzled
  __shared__ __align__(16) char Bb[16384];  // [128q][64r] bf16 swizzled
  const unsigned short* zb = zin + (size_t)b * NN * 512 + i * 128;
  const int tid = threadIdx.x;
  const int lane = tid & 63;
  const int wave = tid >> 6, wp = wave & 1, wq = wave >> 1;
  const int l15 = lane & 15, kq = lane >> 4;
  f32x4 acc[4] = {};
  for (int rc = 0; rc < NN; rc += 64) {
    __syncthreads();
    if (tid < 64) { // stage A: att rows (r-major) -> [p][r], packed transpose
      const int ps = (tid & 3) * 8;
      const int rs = (tid >> 2) * 4;
      u16x8 L[4];
#pragma unroll
      for (int ri = 0; ri < 4; ++ri)
        L[ri] = *(const u16x8*)(att + ((size_t)gi * NN + rc + rs + ri) * NN + pblk + ps);
#pragma unroll
      for (int j = 0; j < 8; ++j) {
        int p = ps + j;
        uint2 pv;
        pv.x = (unsigned int)(unsigned short)L[0][j] | ((unsigned int)(unsigned short)L[1][j] << 16);
        pv.y = (unsigned int)(unsigned short)L[2][j] | ((unsigned int)(unsigned short)L[3][j] << 16);
        *(uint2*)(Ab + ((p * 128 + rs * 2) ^ ((p & 7) << 4))) = pv;
      }
    }
    { // stage B: z rows -> [q][r]
      const int qs = (tid & 15) * 8;
      const int rs = (tid >> 4) * 4;
      u16x8 L[4];
#pragma unroll
      for (int ri = 0; ri < 4; ++ri)
        L[ri] = *(const u16x8*)(zb + (size_t)(rc + rs + ri) * 512 + qs);
#pragma unroll
      for (int j = 0; j < 8; ++j) {
        int q = qs + j;
        uint2 pv;
        pv.x = (unsigned int)(unsigned short)L[0][j] | ((unsigned int)(unsigned short)L[1][j] << 16);
        pv.y = (unsigned int)(unsigned short)L[2][j] | ((unsigned int)(unsigned short)L[3][j] << 16);
        *(uint2*)(Bb + ((q * 128 + rs * 2) ^ ((q & 7) << 4))) = pv;
      }
    }
    __syncthreads();
#pragma unroll
    for (int kk = 0; kk < 2; ++kk) {
      int ml = wp * 16 + l15;
      bf16x8 a = *(const bf16x8*)(Ab + ((ml * 128 + kk * 64 + kq * 16) ^ ((ml & 7) << 4)));
#pragma unroll
      for (int cb = 0; cb < 4; ++cb) {
        int nl = wq * 64 + cb * 16 + l15;
        bf16x8 bf = *(const bf16x8*)(Bb + ((nl * 128 + kk * 64 + kq * 16) ^ ((nl & 7) << 4)));
        acc[cb] = __builtin_amdgcn_mfma_f32_16x16x32_bf16(a, bf, acc[cb], 0, 0, 0);
      }
    }
  }
  __syncthreads(); // staging LDS free; reuse Bb for output retile
  unsigned short* R = (unsigned short*)Bb; // [32][128] bf16 (relu'd acc)
#pragma unroll
  for (int cb = 0; cb < 4; ++cb)
#pragma unroll
    for (int rg = 0; rg < 4; ++rg) {
      int pl = wp * 16 + kq * 4 + rg;
      int q = wq * 64 + cb * 16 + l15;
      R[pl * 128 + q] = f2bf(fmaxf(acc[cb][rg], 0.f));
    }
  __syncthreads();
  const int row = tid >> 3, ch = tid & 7; // 32 rows x 8 chunks
  const int p = pblk + row;
  const size_t gbase = ((size_t)b * NN + p) * 512 + i * 128 + ch * 8;
  u16x8 azv = *(const u16x8*)(R + row * 128 + ch * 8);
  if (h) {
    float bt = beta[((size_t)b * NN + p) * HH + i];
    float om = 1.f - bt;
    u16x8 hv = *(const u16x8*)(h + gbase);
    u16x8 zv;
#pragma unroll
    for (int j = 0; j < 8; ++j)
      zv[j] = f2bf(bt * bf2f((unsigned short)hv[j]) + om * bf2f((unsigned short)azv[j]));
    *(u16x8*)(outp + gbase) = zv;
  } else {
    *(u16x8*)(outp + gbase) = azv;
  }
}

// ---------------- beta[idx] = sigmoid( h·Wb[:D] + az·Wb[D:] + bb ) -------------
__global__ __launch_bounds__(256) void k_beta(const unsigned short* __restrict__ h,
                                              const unsigned short* __restrict__ az,
                                              const float* __restrict__ Wbk,
                                              const float* __restrict__ bbk,
                                              float* __restrict__ beta, int base) {
  const int wid = threadIdx.x >> 6, lane = threadIdx.x & 63;
  const int idx = base + blockIdx.x * 4 + wid; // global (b*N+n)*H + i
  const unsigned short* hp = h + (size_t)idx * 128;
  const unsigned short* ap = az + (size_t)idx * 128;
  float s = 0.f;
#pragma unroll
  for (int e = 0; e < 2; ++e) {
    int d = lane + e * 64;
    s += bf2f(hp[d]) * Wbk[d] + bf2f(ap[d]) * Wbk[128 + d];
  }
#pragma unroll
  for (int off = 32; off; off >>= 1) s += __shfl_xor(s, off);
  if (lane == 0) beta[idx] = 1.f / (1.f + expf(-(s + bbk[0])));
}

// --------- hop-1: z = beta*h + (1-beta)*az  (all bf16; pointers pre-offset) ----
__global__ __launch_bounds__(256) void k_zupd1(const unsigned short* __restrict__ h,
                                               const unsigned short* __restrict__ az,
                                               const float* __restrict__ beta,
                                               unsigned short* __restrict__ z) {
  const int i8 = blockIdx.x * 256 + threadIdx.x; // 8 bf16 per thread
  const float bt = beta[i8 >> 4];
  const float om = 1.f - bt;
  u16x8 hv = *(const u16x8*)(h + (size_t)i8 * 8);
  u16x8 av = *(const u16x8*)(az + (size_t)i8 * 8);
  u16x8 zv;
#pragma unroll
  for (int j = 0; j < 8; ++j)
    zv[j] = f2bf(bt * bf2f((unsigned short)hv[j]) + om * bf2f((unsigned short)av[j]));
  *(u16x8*)(z + (size_t)i8 * 8) = zv;
}

// -------- out[n,d] = mean_i z[n,i,d] (- c1); c fp32 (+bf16); pre-offset --------
__global__ __launch_bounds__(256) void k_headmean(const unsigned short* __restrict__ z,
                                                  const float* __restrict__ c1,
                                                  float* __restrict__ outp,
                                                  unsigned short* __restrict__ outbf) {
  const int idx = blockIdx.x * 256 + threadIdx.x; // over group's N*D
  const int d = idx & 127, bn = idx >> 7;
  const size_t base = (size_t)bn * 512 + d;
  float v = 0.25f * (bf2f(z[base]) + bf2f(z[base + 128]) +
                     bf2f(z[base + 256]) + bf2f(z[base + 384]));
  if (c1) v -= c1[idx];
  outp[idx] = v;
  if (outbf) outbf[idx] = f2bf(v);
}

// ---------------- node mean + MLP head ----------------------------------------
__global__ __launch_bounds__(128) void k_final(const float* __restrict__ c,
                                               const float* __restrict__ valid,
                                               const float* __restrict__ Wfc0,
                                               const float* __restrict__ bfc0,
                                               const float* __restrict__ Wfcm,
                                               const float* __restrict__ bfcm,
                                               const float* __restrict__ Wfcl,
                                               const float* __restrict__ bfcl,
                                               float* __restrict__ out) {
  const int b = blockIdx.x, d = threadIdx.x;
  __shared__ float bufA[128], bufB[128], red[128];
  float s = 0.f, vs = 0.f;
  for (int n = 0; n < NN; ++n) {
    float vv = valid[b * NN + n];
    s += c[((size_t)b * NN + n) * 128 + d] * vv;
    vs += vv;
  }
  bufA[d] = s / vs;
  __syncthreads();
  float t = bfc0[d];
  for (int m = 0; m < 128; ++m) t += bufA[m] * Wfc0[m * 128 + d];
  bufB[d] = fmaxf(t, 0.f);
  __syncthreads();
  t = bfcm[d];
  for (int m = 0; m < 128; ++m) t += bufB[m] * Wfcm[m * 128 + d];
  bufA[d] = fmaxf(t, 0.f);
  __syncthreads();
  t = bfcm[128 + d];
  for (int m = 0; m < 128; ++m) t += bufA[m] * Wfcm[128 * 128 + m * 128 + d];
  bufB[d] = fmaxf(t, 0.f);
  __syncthreads();
  red[d] = bufB[d] * Wfcl[d];
  __syncthreads();
  for (int st = 64; st; st >>= 1) {
    if (d < st) red[d] += red[d + st];
    __syncthreads();
  }
  if (d == 0) out[b] = 1.f / (1.f + expf(-(red[0] + bfcl[0])));
}

extern "C" void kernel_launch(void* const* d_in, const int* in_sizes, int n_in,
                              void* d_out, int out_size, void* d_ws, size_t ws_size,
                              hipStream_t stream) {
  (void)in_sizes; (void)n_in; (void)out_size;
  const float* x     = (const float*)d_in[0];
  const float* adj1  = (const float*)d_in[1];
  const float* adj2  = (const float*)d_in[2];
  const float* valid = (const float*)d_in[3];
  const float* Wemb  = (const float*)d_in[4];
  const float* Wh    = (const float*)d_in[5];
  const float* bh    = (const float*)d_in[6];
  const float* We    = (const float*)d_in[7];
  const float* Wb    = (const float*)d_in[8];
  const float* bb    = (const float*)d_in[9];
  const float* Wfc0  = (const float*)d_in[10];
  const float* bfc0  = (const float*)d_in[11];
  const float* Wfcm  = (const float*)d_in[12];
  const float* bfcm  = (const float*)d_in[13];
  const float* Wfcl  = (const float*)d_in[14];
  const float* bfcl  = (const float*)d_in[15];
  float* out = (float*)d_out;

  // ---- workspace layout (fp32-element offsets; adaptive e-group) ----
  float* w = (float*)d_ws;
  size_t off = 0;
  float* c    = w + off; off += (size_t)BB * NN * DD;        // 4 MB
  float* c1   = w + off; off += (size_t)BB * NN * DD;        // 4 MB
  float* beta = w + off; off += (size_t)BB * NN * HH;        // 128 KB
  unsigned short* c_bf = (unsigned short*)(w + off); off += (size_t)BB * NN * DD / 2;      // 2 MB
  unsigned short* h_bf = (unsigned short*)(w + off); off += (size_t)BB * NN * HH * DD / 2; // 8 MB
  unsigned short* g_bf = (unsigned short*)(w + off); off += (size_t)BB * NN * HH * DD / 2; // 8 MB
  unsigned short* zA   = (unsigned short*)(w + off); off += (size_t)BB * NN * HH * DD / 2; // 8 MB
  unsigned short* zB   = (unsigned short*)(w + off); off += (size_t)BB * NN * HH * DD / 2; // 8 MB
  unsigned short* azb  = (unsigned short*)(w + off); off += (size_t)BB * NN * HH * DD / 2; // 8 MB
  unsigned short* WhT  = (unsigned short*)(w + off); off += (size_t)LL * 512 * 128 / 2;    // 512 KB
  unsigned short* WeT  = (unsigned short*)(w + off); off += (size_t)LL * 128 * 128 / 2;    // 128 KB
  const size_t fixedBytes = off * 4;
  const size_t adjTBytes = 2ull * BB * NN * NN * 2;          // 32 MB
  const size_t eGroupBytes = (size_t)HH * NN * NN * 2;       // 8 MB per batch

  int G = 8;
  while (G > 1 && fixedBytes + adjTBytes + (size_t)G * eGroupBytes > ws_size) G >>= 1;
  bool useAdjT = (fixedBytes + adjTBytes + (size_t)G * eGroupBytes <= ws_size);

  unsigned short* adjT1 = (unsigned short*)(w + off);
  unsigned short* adjT2 = adjT1 + (size_t)BB * NN * NN;
  unsigned short* e = useAdjT ? (adjT2 + (size_t)BB * NN * NN) : (unsigned short*)(w + off);

  if (useAdjT) {
    k_transpose_bf16<<<dim3(32, 32, BB), 256, 0, stream>>>(adj1, adjT1);
    k_transpose_bf16<<<dim3(32, 32, BB), 256, 0, stream>>>(adj2, adjT2);
  }
  k_wtrans<<<dim3(4, 16, LL), 256, 0, stream>>>(Wh, WhT, 512);
  k_wtrans<<<dim3(4, 4, LL), 256, 0, stream>>>(We, WeT, 128);
  // c = x @ W_embede  (fp32 SIMT, once)
  k_gemm_k128<<<dim3(128, 2), 256, 0, stream>>>(x, Wemb, c, c_bf, BB * NN, DD);

  for (int k = 0; k < LL; ++k) {
    for (int br = 0; br < 2; ++br) {
      const float* adjcur = (br == 0) ? adj1 : adj2;
      const unsigned short* adjTcur = useAdjT ? ((br == 0) ? adjT1 : adjT2) : nullptr;
      // h = c @ Wh_k + bh_k  -> [8192, 512] bf16
      k_gemm_nt<<<dim3(128, 8), 256, 0, stream>>>(
          c_bf, WhT + (size_t)k * 512 * 128, bh + (size_t)k * 512, h_bf, 512);
      // g = h @ We_k         -> [32768, 128] bf16
      k_gemm_nt<<<dim3(512, 2), 256, 0, stream>>>(
          h_bf, WeT + (size_t)k * 128 * 128, nullptr, g_bf, 128);
      for (int b0 = 0; b0 < BB; b0 += G) {
        const size_t oH = (size_t)b0 * NN * 512;  // bf16-elem offset into h/z/az
        const size_t oB = (size_t)b0 * NN * HH;
        const size_t oC = (size_t)b0 * NN * DD;
        k_e_mfma<<<dim3(16, 16, G * HH), 256, 0, stream>>>(g_bf, h_bf, e, b0);
        k_soft<<<G * HH * NN, 256, 0, stream>>>(e, adjTcur, adjcur, b0);
        k_az_mfma<<<dim3(32, G * HH), 256, 0, stream>>>(e, h_bf, nullptr, nullptr, azb, b0);
        k_beta<<<G * NN * HH / 4, 256, 0, stream>>>(h_bf, azb, Wb + (size_t)k * 2 * DD,
                                                    bb + k, beta, (int)oB);
        k_zupd1<<<G * 256, 256, 0, stream>>>(h_bf + oH, azb + oH, beta + oB, zA + oH);
        unsigned short* cur = zA;
        unsigned short* nxt = zB;
        for (int t = 2; t <= k + 1; ++t) {
          k_az_mfma<<<dim3(32, G * HH), 256, 0, stream>>>(e, cur, h_bf, beta, nxt, b0);
          unsigned short* tmp = cur; cur = nxt; nxt = tmp;
        }
        k_headmean<<<G * 512, 256, 0, stream>>>(
            cur + oH, (br == 0) ? nullptr : (c1 + oC), ((br == 0) ? c1 : c) + oC,
            (br == 0) ? nullptr : (c_bf + oC));
      }
    }
  }
  k_final<<<BB, 128, 0, stream>>>(c, valid, Wfc0, bfc0, Wfcm, bfcm, Wfcl, bfcl, out);
}